// Round 22
// baseline (84.978 us; speedup 1.0000x reference)
//
#include <hip/hip_runtime.h>
#include <hip/hip_bf16.h>

#define NROWS 16384   // B*S
#define KD    2048    // D
#define NE    16      // experts
#define ROWS_PER_BLK 32
#define NT    32      // K tiles of 64 floats (full K per wave)

// v19b: expert-PAIR waves + x register prefetch (fixed token-paste: suffix _A/_B).
//  - block = 512 thr / 8 waves / 32 rows; grid 512 = 2 blocks/CU = 4 waves/SIMD
//  - wave w = expert pair ep (2 experts x 2 mats); lane = (rgrp -> 4 rows, seg)
//  - acc = 4 rows x 2 e x 2 m = 16 floats; x double-buffered in regs (2x32)
//  - W tile [32][64] dbuf in LDS (16 KB), exactly 1 global_load_lds per thread
//  - FMA:ds_read = 16:1; per-CU ds_read = 4096 instrs (same as v17)
//  - epilogue: seg-butterfly -> slab[32][33] -> per-row softplus/top2/softmax
// Output FLOAT32: [262144 probs][32768 ids-as-floats].

__device__ __forceinline__ void gload_lds16(const float* g, float* l) {
    __builtin_amdgcn_global_load_lds(
        (const __attribute__((address_space(1))) void*)g,
        (__attribute__((address_space(3))) void*)l,
        16, 0, 0);
}

__global__ __launch_bounds__(512)
void noisy_router_kernel(const float* __restrict__ x,
                         const float* __restrict__ noise,
                         const float* __restrict__ Wfc,
                         const float* __restrict__ bfc,
                         const float* __restrict__ Wns,
                         const float* __restrict__ bns,
                         float* __restrict__ out)
{
    __shared__ float lds[4096];    // 16 KB: wt0[32*64] + wt1[32*64]; slab reuse

    const int tid  = threadIdx.x;
    const int lane = tid & 63;
    const int ep   = tid >> 6;     // wave = expert pair 0..7
    const int seg  = lane & 7;
    const int rgrp = lane >> 3;

    const int rowbase = blockIdx.x * ROWS_PER_BLK + rgrp * 4;

    float* const wt0 = lds;
    float* const wt1 = lds + 2048;

    // staging (1 instr/thread, 512x16B = full 8KB tile):
    // W-stack row tid>>4 (0..15 = Wfc experts, 16..31 = Wns), slot tid&15.
    // dest byte = tid*16  (wave-uniform base + lane*16: legal linear form)
    const int wr = tid >> 4;
    const float* wsrc = (wr < 16 ? Wfc + (size_t)wr * KD
                                 : Wns + (size_t)(wr - 16) * KD) + (tid & 15) * 4;
    const int sdst = tid * 4;      // float offset

    const float* xb = x + (size_t)rowbase * KD + seg * 8;

    float accA[4][2], accB[4][2];          // [row j][expert e] -- 16 floats
    #pragma unroll
    for (int j = 0; j < 4; ++j)
        #pragma unroll
        for (int e = 0; e < 2; ++e) { accA[j][e] = 0.f; accB[j][e] = 0.f; }

    // two named x register sets (suffix _A/_B), 8 float4 each
    float4 x0a_A, x0b_A, x1a_A, x1b_A, x2a_A, x2b_A, x3a_A, x3b_A;
    float4 x0a_B, x0b_B, x1a_B, x1b_B, x2a_B, x2b_B, x3a_B, x3b_B;

#define STAGE(DST, T) gload_lds16(wsrc + (T) * 64, (DST) + sdst);

#define XLOAD(S, T) { \
    x0a_##S = *(const float4*)(xb + 0 * KD + (T) * 64);       \
    x0b_##S = *(const float4*)(xb + 0 * KD + (T) * 64 + 4);   \
    x1a_##S = *(const float4*)(xb + 1 * KD + (T) * 64);       \
    x1b_##S = *(const float4*)(xb + 1 * KD + (T) * 64 + 4);   \
    x2a_##S = *(const float4*)(xb + 2 * KD + (T) * 64);       \
    x2b_##S = *(const float4*)(xb + 2 * KD + (T) * 64 + 4);   \
    x3a_##S = *(const float4*)(xb + 3 * KD + (T) * 64);       \
    x3b_##S = *(const float4*)(xb + 3 * KD + (T) * 64 + 4); }

#define COMPUTE(WT, S) { \
    const float* wpA = (WT) + ep * 128 + seg * 8;               \
    const float* wpB = wpA + 1024;                              \
    _Pragma("unroll")                                           \
    for (int e = 0; e < 2; ++e) {                               \
        const float4 a0 = *(const float4*)(wpA + e * 64);       \
        const float4 a1 = *(const float4*)(wpA + e * 64 + 4);   \
        const float4 b0 = *(const float4*)(wpB + e * 64);       \
        const float4 b1 = *(const float4*)(wpB + e * 64 + 4);   \
        accA[0][e] = fmaf(x0a_##S.x, a0.x, accA[0][e]);         \
        accA[0][e] = fmaf(x0a_##S.y, a0.y, accA[0][e]);         \
        accA[0][e] = fmaf(x0a_##S.z, a0.z, accA[0][e]);         \
        accA[0][e] = fmaf(x0a_##S.w, a0.w, accA[0][e]);         \
        accA[0][e] = fmaf(x0b_##S.x, a1.x, accA[0][e]);         \
        accA[0][e] = fmaf(x0b_##S.y, a1.y, accA[0][e]);         \
        accA[0][e] = fmaf(x0b_##S.z, a1.z, accA[0][e]);         \
        accA[0][e] = fmaf(x0b_##S.w, a1.w, accA[0][e]);         \
        accB[0][e] = fmaf(x0a_##S.x, b0.x, accB[0][e]);         \
        accB[0][e] = fmaf(x0a_##S.y, b0.y, accB[0][e]);         \
        accB[0][e] = fmaf(x0a_##S.z, b0.z, accB[0][e]);         \
        accB[0][e] = fmaf(x0a_##S.w, b0.w, accB[0][e]);         \
        accB[0][e] = fmaf(x0b_##S.x, b1.x, accB[0][e]);         \
        accB[0][e] = fmaf(x0b_##S.y, b1.y, accB[0][e]);         \
        accB[0][e] = fmaf(x0b_##S.z, b1.z, accB[0][e]);         \
        accB[0][e] = fmaf(x0b_##S.w, b1.w, accB[0][e]);         \
        accA[1][e] = fmaf(x1a_##S.x, a0.x, accA[1][e]);         \
        accA[1][e] = fmaf(x1a_##S.y, a0.y, accA[1][e]);         \
        accA[1][e] = fmaf(x1a_##S.z, a0.z, accA[1][e]);         \
        accA[1][e] = fmaf(x1a_##S.w, a0.w, accA[1][e]);         \
        accA[1][e] = fmaf(x1b_##S.x, a1.x, accA[1][e]);         \
        accA[1][e] = fmaf(x1b_##S.y, a1.y, accA[1][e]);         \
        accA[1][e] = fmaf(x1b_##S.z, a1.z, accA[1][e]);         \
        accA[1][e] = fmaf(x1b_##S.w, a1.w, accA[1][e]);         \
        accB[1][e] = fmaf(x1a_##S.x, b0.x, accB[1][e]);         \
        accB[1][e] = fmaf(x1a_##S.y, b0.y, accB[1][e]);         \
        accB[1][e] = fmaf(x1a_##S.z, b0.z, accB[1][e]);         \
        accB[1][e] = fmaf(x1a_##S.w, b0.w, accB[1][e]);         \
        accB[1][e] = fmaf(x1b_##S.x, b1.x, accB[1][e]);         \
        accB[1][e] = fmaf(x1b_##S.y, b1.y, accB[1][e]);         \
        accB[1][e] = fmaf(x1b_##S.z, b1.z, accB[1][e]);         \
        accB[1][e] = fmaf(x1b_##S.w, b1.w, accB[1][e]);         \
        accA[2][e] = fmaf(x2a_##S.x, a0.x, accA[2][e]);         \
        accA[2][e] = fmaf(x2a_##S.y, a0.y, accA[2][e]);         \
        accA[2][e] = fmaf(x2a_##S.z, a0.z, accA[2][e]);         \
        accA[2][e] = fmaf(x2a_##S.w, a0.w, accA[2][e]);         \
        accA[2][e] = fmaf(x2b_##S.x, a1.x, accA[2][e]);         \
        accA[2][e] = fmaf(x2b_##S.y, a1.y, accA[2][e]);         \
        accA[2][e] = fmaf(x2b_##S.z, a1.z, accA[2][e]);         \
        accA[2][e] = fmaf(x2b_##S.w, a1.w, accA[2][e]);         \
        accB[2][e] = fmaf(x2a_##S.x, b0.x, accB[2][e]);         \
        accB[2][e] = fmaf(x2a_##S.y, b0.y, accB[2][e]);         \
        accB[2][e] = fmaf(x2a_##S.z, b0.z, accB[2][e]);         \
        accB[2][e] = fmaf(x2a_##S.w, b0.w, accB[2][e]);         \
        accB[2][e] = fmaf(x2b_##S.x, b1.x, accB[2][e]);         \
        accB[2][e] = fmaf(x2b_##S.y, b1.y, accB[2][e]);         \
        accB[2][e] = fmaf(x2b_##S.z, b1.z, accB[2][e]);         \
        accB[2][e] = fmaf(x2b_##S.w, b1.w, accB[2][e]);         \
        accA[3][e] = fmaf(x3a_##S.x, a0.x, accA[3][e]);         \
        accA[3][e] = fmaf(x3a_##S.y, a0.y, accA[3][e]);         \
        accA[3][e] = fmaf(x3a_##S.z, a0.z, accA[3][e]);         \
        accA[3][e] = fmaf(x3a_##S.w, a0.w, accA[3][e]);         \
        accA[3][e] = fmaf(x3b_##S.x, a1.x, accA[3][e]);         \
        accA[3][e] = fmaf(x3b_##S.y, a1.y, accA[3][e]);         \
        accA[3][e] = fmaf(x3b_##S.z, a1.z, accA[3][e]);         \
        accA[3][e] = fmaf(x3b_##S.w, a1.w, accA[3][e]);         \
        accB[3][e] = fmaf(x3a_##S.x, b0.x, accB[3][e]);         \
        accB[3][e] = fmaf(x3a_##S.y, b0.y, accB[3][e]);         \
        accB[3][e] = fmaf(x3a_##S.z, b0.z, accB[3][e]);         \
        accB[3][e] = fmaf(x3a_##S.w, b0.w, accB[3][e]);         \
        accB[3][e] = fmaf(x3b_##S.x, b1.x, accB[3][e]);         \
        accB[3][e] = fmaf(x3b_##S.y, b1.y, accB[3][e]);         \
        accB[3][e] = fmaf(x3b_##S.z, b1.z, accB[3][e]);         \
        accB[3][e] = fmaf(x3b_##S.w, b1.w, accB[3][e]);         \
    } }

    // prologue: W tile 0 + x tile 0
    STAGE(wt0, 0)
    XLOAD(A, 0)

    #pragma unroll 1
    for (int tp = 0; tp < NT; tp += 2) {
        __syncthreads();               // stage(tp) + XLOAD done (vmcnt drained)
        XLOAD(B, tp + 1)               // prefetch next x (covered by this body+barrier)
        STAGE(wt1, tp + 1)             // prefetch next W
        COMPUTE(wt0, A)
        __syncthreads();               // stage(tp+1) + XLOAD(B) done
        if (tp + 2 < NT) {
            XLOAD(A, tp + 2)
            STAGE(wt0, tp + 2)
        }
        COMPUTE(wt1, B)
    }
#undef STAGE
#undef XLOAD
#undef COMPUTE

    // ---- butterfly over the 8 k-segs (masks 1,2,4 stay within seg-group) ----
    #pragma unroll
    for (int j = 0; j < 4; ++j)
        #pragma unroll
        for (int e = 0; e < 2; ++e) {
            float a = accA[j][e], b = accB[j][e];
            a += __shfl_xor(a, 1); a += __shfl_xor(a, 2); a += __shfl_xor(a, 4);
            b += __shfl_xor(b, 1); b += __shfl_xor(b, 2); b += __shfl_xor(b, 4);
            accA[j][e] = a; accB[j][e] = b;
        }

    __syncthreads();                  // all tile reads done; lds reusable as slab
    float* const slab = lds;          // [32 rows][stride 33]

    if (seg == 0) {                   // each wave owns (4 rows x expert-pair) outs
        #pragma unroll
        for (int j = 0; j < 4; ++j) {
            float* dst = slab + (rgrp * 4 + j) * 33 + ep * 2;
            dst[0]  = accA[j][0]; dst[1]  = accA[j][1];
            dst[16] = accB[j][0]; dst[17] = accB[j][1];
        }
    }
    __syncthreads();

    // ---- per-row epilogue: softplus noise, top-2, sparse softmax ----
    if (tid < ROWS_PER_BLK) {
        const int r = tid;
        const float* rowp = slab + r * 33;
        const size_t grow = (size_t)blockIdx.x * ROWS_PER_BLK + r;
        const float* nzp = noise + grow * NE;

        float m1 = -1e30f, m2 = -1e30f;
        int i1 = 0, i2 = 0;
        #pragma unroll
        for (int j = 0; j < NE; ++j) {
            const float z  = rowp[16 + j] + bns[j];
            const float sp = fmaxf(z, 0.f) + log1pf(expf(-fabsf(z)));  // jax softplus
            const float v  = fmaf(nzp[j], sp, rowp[j] + bfc[j]);
            if (v > m1)      { m2 = m1; i2 = i1; m1 = v; i1 = j; }     // ties -> lower idx
            else if (v > m2) { m2 = v;  i2 = j; }
        }
        const float e2  = expf(m2 - m1);
        const float inv = 1.f / (1.f + e2);

        float* po = out + grow * NE;
        #pragma unroll
        for (int j = 0; j < NE; ++j) {
            po[j] = (j == i1) ? inv : ((j == i2) ? e2 * inv : 0.f);
        }
        float* pi = out + (size_t)NROWS * NE + grow * 2;
        pi[0] = (float)i1;
        pi[1] = (float)i2;
    }
}

extern "C" void kernel_launch(void* const* d_in, const int* in_sizes, int n_in,
                              void* d_out, int out_size, void* d_ws, size_t ws_size,
                              hipStream_t stream)
{
    const float* x     = (const float*)d_in[0];
    const float* noise = (const float*)d_in[1];
    const float* Wfc   = (const float*)d_in[2];
    const float* bfc   = (const float*)d_in[3];
    const float* Wns   = (const float*)d_in[4];
    const float* bns   = (const float*)d_in[5];
    float* out = (float*)d_out;

    noisy_router_kernel<<<NROWS / ROWS_PER_BLK, 512, 0, stream>>>(
        x, noise, Wfc, bfc, Wns, bns, out);
}

// Round 23
// 58.282 us; speedup vs baseline: 1.4580x; 1.4580x over previous
//
#include <hip/hip_runtime.h>
#include <hip/hip_bf16.h>

#define NROWS 16384   // B*S
#define KD    2048    // D
#define NE    16      // experts
#define ROWS_PER_BLK 64
#define NT    32      // K tiles of 64 floats (full K per wave)

// v20 = v17 (56.9us champion) + x register double-buffer (_A/_B named sets).
//  - block = 512 thr / 8 waves / 64 rows; grid 256 = 1 block/CU
//  - wave w -> (expert-quartet eq=w&3, row-half rh=w>>2); 4x x-duplication only
//  - lane = (rgrp=lane>>3 -> 4 rows, seg=lane&7 -> 8-float K-slice per tile)
//  - acc = 4 rows x 4 e x 2 m = 32 floats; x 2x32 regs -> ~124 VGPR (<=128)
//  - W tile [32][64] dbuf in LDS (16 KB), 1 global_load_lds per thread
//  - body: XLOAD(next)+STAGE(next) first, COMPUTE(cur) consumes prev-loaded x
//    -> x latency hidden behind ~1024cy FMA; barrier vmcnt drain covered
// Output FLOAT32: [262144 probs][32768 ids-as-floats].

__device__ __forceinline__ void gload_lds16(const float* g, float* l) {
    __builtin_amdgcn_global_load_lds(
        (const __attribute__((address_space(1))) void*)g,
        (__attribute__((address_space(3))) void*)l,
        16, 0, 0);
}

__global__ __launch_bounds__(512)
void noisy_router_kernel(const float* __restrict__ x,
                         const float* __restrict__ noise,
                         const float* __restrict__ Wfc,
                         const float* __restrict__ bfc,
                         const float* __restrict__ Wns,
                         const float* __restrict__ bns,
                         float* __restrict__ out)
{
    __shared__ float lds[4096];    // 16 KB: wt0[32*64] + wt1[32*64]; slab reuse

    const int tid  = threadIdx.x;
    const int lane = tid & 63;
    const int w    = tid >> 6;     // 0..7
    const int eq   = w & 3;        // expert quartet 0..3
    const int rh   = w >> 2;       // row half 0..1
    const int seg  = lane & 7;
    const int rgrp = lane >> 3;

    const int rowbase = blockIdx.x * ROWS_PER_BLK + rh * 32 + rgrp * 4;

    float* const wt0 = lds;
    float* const wt1 = lds + 2048;

    // staging (1 instr/thread): LDS row = w*4 + (lane>>4) (0..15 = Wfc,
    // 16..31 = Wns), col = (lane&15)*4 -> dest = w*1024B + lane*16B (legal).
    const int srow = w * 4 + (lane >> 4);
    const float* wsrc = (srow < 16 ? Wfc + (size_t)srow * KD
                                   : Wns + (size_t)(srow - 16) * KD) + (lane & 15) * 4;
    const int sdst = srow * 64 + (lane & 15) * 4;

    const float* xb = x + (size_t)rowbase * KD + seg * 8;

    float accA[4][4], accB[4][4];          // [row j][expert e] -- 32 floats
    #pragma unroll
    for (int j = 0; j < 4; ++j)
        #pragma unroll
        for (int e = 0; e < 4; ++e) { accA[j][e] = 0.f; accB[j][e] = 0.f; }

    // two named x register sets (suffix _A/_B), 8 float4 each
    float4 x0a_A, x0b_A, x1a_A, x1b_A, x2a_A, x2b_A, x3a_A, x3b_A;
    float4 x0a_B, x0b_B, x1a_B, x1b_B, x2a_B, x2b_B, x3a_B, x3b_B;

#define STAGE(DST, T) gload_lds16(wsrc + (T) * 64, (DST) + sdst);

#define XLOAD(S, T) { \
    x0a_##S = *(const float4*)(xb + 0 * KD + (T) * 64);       \
    x0b_##S = *(const float4*)(xb + 0 * KD + (T) * 64 + 4);   \
    x1a_##S = *(const float4*)(xb + 1 * KD + (T) * 64);       \
    x1b_##S = *(const float4*)(xb + 1 * KD + (T) * 64 + 4);   \
    x2a_##S = *(const float4*)(xb + 2 * KD + (T) * 64);       \
    x2b_##S = *(const float4*)(xb + 2 * KD + (T) * 64 + 4);   \
    x3a_##S = *(const float4*)(xb + 3 * KD + (T) * 64);       \
    x3b_##S = *(const float4*)(xb + 3 * KD + (T) * 64 + 4); }

#define COMPUTE(WT, S) { \
    const float* wpA = (WT) + eq * 256 + seg * 8;               \
    const float* wpB = wpA + 1024;                              \
    _Pragma("unroll")                                           \
    for (int e = 0; e < 4; ++e) {                               \
        const float4 a0 = *(const float4*)(wpA + e * 64);       \
        const float4 a1 = *(const float4*)(wpA + e * 64 + 4);   \
        const float4 b0 = *(const float4*)(wpB + e * 64);       \
        const float4 b1 = *(const float4*)(wpB + e * 64 + 4);   \
        accA[0][e] = fmaf(x0a_##S.x, a0.x, accA[0][e]);         \
        accA[0][e] = fmaf(x0a_##S.y, a0.y, accA[0][e]);         \
        accA[0][e] = fmaf(x0a_##S.z, a0.z, accA[0][e]);         \
        accA[0][e] = fmaf(x0a_##S.w, a0.w, accA[0][e]);         \
        accA[0][e] = fmaf(x0b_##S.x, a1.x, accA[0][e]);         \
        accA[0][e] = fmaf(x0b_##S.y, a1.y, accA[0][e]);         \
        accA[0][e] = fmaf(x0b_##S.z, a1.z, accA[0][e]);         \
        accA[0][e] = fmaf(x0b_##S.w, a1.w, accA[0][e]);         \
        accB[0][e] = fmaf(x0a_##S.x, b0.x, accB[0][e]);         \
        accB[0][e] = fmaf(x0a_##S.y, b0.y, accB[0][e]);         \
        accB[0][e] = fmaf(x0a_##S.z, b0.z, accB[0][e]);         \
        accB[0][e] = fmaf(x0a_##S.w, b0.w, accB[0][e]);         \
        accB[0][e] = fmaf(x0b_##S.x, b1.x, accB[0][e]);         \
        accB[0][e] = fmaf(x0b_##S.y, b1.y, accB[0][e]);         \
        accB[0][e] = fmaf(x0b_##S.z, b1.z, accB[0][e]);         \
        accB[0][e] = fmaf(x0b_##S.w, b1.w, accB[0][e]);         \
        accA[1][e] = fmaf(x1a_##S.x, a0.x, accA[1][e]);         \
        accA[1][e] = fmaf(x1a_##S.y, a0.y, accA[1][e]);         \
        accA[1][e] = fmaf(x1a_##S.z, a0.z, accA[1][e]);         \
        accA[1][e] = fmaf(x1a_##S.w, a0.w, accA[1][e]);         \
        accA[1][e] = fmaf(x1b_##S.x, a1.x, accA[1][e]);         \
        accA[1][e] = fmaf(x1b_##S.y, a1.y, accA[1][e]);         \
        accA[1][e] = fmaf(x1b_##S.z, a1.z, accA[1][e]);         \
        accA[1][e] = fmaf(x1b_##S.w, a1.w, accA[1][e]);         \
        accB[1][e] = fmaf(x1a_##S.x, b0.x, accB[1][e]);         \
        accB[1][e] = fmaf(x1a_##S.y, b0.y, accB[1][e]);         \
        accB[1][e] = fmaf(x1a_##S.z, b0.z, accB[1][e]);         \
        accB[1][e] = fmaf(x1a_##S.w, b0.w, accB[1][e]);         \
        accB[1][e] = fmaf(x1b_##S.x, b1.x, accB[1][e]);         \
        accB[1][e] = fmaf(x1b_##S.y, b1.y, accB[1][e]);         \
        accB[1][e] = fmaf(x1b_##S.z, b1.z, accB[1][e]);         \
        accB[1][e] = fmaf(x1b_##S.w, b1.w, accB[1][e]);         \
        accA[2][e] = fmaf(x2a_##S.x, a0.x, accA[2][e]);         \
        accA[2][e] = fmaf(x2a_##S.y, a0.y, accA[2][e]);         \
        accA[2][e] = fmaf(x2a_##S.z, a0.z, accA[2][e]);         \
        accA[2][e] = fmaf(x2a_##S.w, a0.w, accA[2][e]);         \
        accA[2][e] = fmaf(x2b_##S.x, a1.x, accA[2][e]);         \
        accA[2][e] = fmaf(x2b_##S.y, a1.y, accA[2][e]);         \
        accA[2][e] = fmaf(x2b_##S.z, a1.z, accA[2][e]);         \
        accA[2][e] = fmaf(x2b_##S.w, a1.w, accA[2][e]);         \
        accB[2][e] = fmaf(x2a_##S.x, b0.x, accB[2][e]);         \
        accB[2][e] = fmaf(x2a_##S.y, b0.y, accB[2][e]);         \
        accB[2][e] = fmaf(x2a_##S.z, b0.z, accB[2][e]);         \
        accB[2][e] = fmaf(x2a_##S.w, b0.w, accB[2][e]);         \
        accB[2][e] = fmaf(x2b_##S.x, b1.x, accB[2][e]);         \
        accB[2][e] = fmaf(x2b_##S.y, b1.y, accB[2][e]);         \
        accB[2][e] = fmaf(x2b_##S.z, b1.z, accB[2][e]);         \
        accB[2][e] = fmaf(x2b_##S.w, b1.w, accB[2][e]);         \
        accA[3][e] = fmaf(x3a_##S.x, a0.x, accA[3][e]);         \
        accA[3][e] = fmaf(x3a_##S.y, a0.y, accA[3][e]);         \
        accA[3][e] = fmaf(x3a_##S.z, a0.z, accA[3][e]);         \
        accA[3][e] = fmaf(x3a_##S.w, a0.w, accA[3][e]);         \
        accA[3][e] = fmaf(x3b_##S.x, a1.x, accA[3][e]);         \
        accA[3][e] = fmaf(x3b_##S.y, a1.y, accA[3][e]);         \
        accA[3][e] = fmaf(x3b_##S.z, a1.z, accA[3][e]);         \
        accA[3][e] = fmaf(x3b_##S.w, a1.w, accA[3][e]);         \
        accB[3][e] = fmaf(x3a_##S.x, b0.x, accB[3][e]);         \
        accB[3][e] = fmaf(x3a_##S.y, b0.y, accB[3][e]);         \
        accB[3][e] = fmaf(x3a_##S.z, b0.z, accB[3][e]);         \
        accB[3][e] = fmaf(x3a_##S.w, b0.w, accB[3][e]);         \
        accB[3][e] = fmaf(x3b_##S.x, b1.x, accB[3][e]);         \
        accB[3][e] = fmaf(x3b_##S.y, b1.y, accB[3][e]);         \
        accB[3][e] = fmaf(x3b_##S.z, b1.z, accB[3][e]);         \
        accB[3][e] = fmaf(x3b_##S.w, b1.w, accB[3][e]);         \
    } }

    // prologue: W tile 0 + x tile 0
    STAGE(wt0, 0)
    XLOAD(A, 0)

    #pragma unroll 1
    for (int tp = 0; tp < NT; tp += 2) {
        __syncthreads();               // stage(tp) + x(tp) ready (vmcnt drained)
        XLOAD(B, tp + 1)               // prefetch next x (hidden under COMPUTE)
        STAGE(wt1, tp + 1)             // prefetch next W
        COMPUTE(wt0, A)
        __syncthreads();               // stage(tp+1) + x(tp+1) ready
        if (tp + 2 < NT) {
            XLOAD(A, tp + 2)
            STAGE(wt0, tp + 2)
        }
        COMPUTE(wt1, B)
    }
#undef STAGE
#undef XLOAD
#undef COMPUTE

    // ---- butterfly over the 8 k-segs (masks 1,2,4 stay within seg-group) ----
    #pragma unroll
    for (int j = 0; j < 4; ++j)
        #pragma unroll
        for (int e = 0; e < 4; ++e) {
            float a = accA[j][e], b = accB[j][e];
            a += __shfl_xor(a, 1); a += __shfl_xor(a, 2); a += __shfl_xor(a, 4);
            b += __shfl_xor(b, 1); b += __shfl_xor(b, 2); b += __shfl_xor(b, 4);
            accA[j][e] = a; accB[j][e] = b;
        }

    __syncthreads();                  // all tile reads done; lds reusable as slab
    float* const slab = lds;          // [64 rows][stride 33] = 8448 B

    if (seg == 0) {                   // each wave owns complete (row, e-quartet) outs
        #pragma unroll
        for (int j = 0; j < 4; ++j) {
            float* dst = slab + (rh * 32 + rgrp * 4 + j) * 33 + eq * 4;
            #pragma unroll
            for (int e = 0; e < 4; ++e) { dst[e] = accA[j][e]; dst[16 + e] = accB[j][e]; }
        }
    }
    __syncthreads();

    // ---- per-row epilogue: softplus noise, top-2, sparse softmax ----
    if (tid < ROWS_PER_BLK) {
        const int r = tid;
        const float* rowp = slab + r * 33;
        const size_t grow = (size_t)blockIdx.x * ROWS_PER_BLK + r;
        const float* nzp = noise + grow * NE;

        float m1 = -1e30f, m2 = -1e30f;
        int i1 = 0, i2 = 0;
        #pragma unroll
        for (int j = 0; j < NE; ++j) {
            const float z  = rowp[16 + j] + bns[j];
            const float sp = fmaxf(z, 0.f) + log1pf(expf(-fabsf(z)));  // jax softplus
            const float v  = fmaf(nzp[j], sp, rowp[j] + bfc[j]);
            if (v > m1)      { m2 = m1; i2 = i1; m1 = v; i1 = j; }     // ties -> lower idx
            else if (v > m2) { m2 = v;  i2 = j; }
        }
        const float e2  = expf(m2 - m1);
        const float inv = 1.f / (1.f + e2);

        float* po = out + grow * NE;
        #pragma unroll
        for (int j = 0; j < NE; ++j) {
            po[j] = (j == i1) ? inv : ((j == i2) ? e2 * inv : 0.f);
        }
        float* pi = out + (size_t)NROWS * NE + grow * 2;
        pi[0] = (float)i1;
        pi[1] = (float)i2;
    }
}

extern "C" void kernel_launch(void* const* d_in, const int* in_sizes, int n_in,
                              void* d_out, int out_size, void* d_ws, size_t ws_size,
                              hipStream_t stream)
{
    const float* x     = (const float*)d_in[0];
    const float* noise = (const float*)d_in[1];
    const float* Wfc   = (const float*)d_in[2];
    const float* bfc   = (const float*)d_in[3];
    const float* Wns   = (const float*)d_in[4];
    const float* bns   = (const float*)d_in[5];
    float* out = (float*)d_out;

    noisy_router_kernel<<<NROWS / ROWS_PER_BLK, 512, 0, stream>>>(
        x, noise, Wfc, bfc, Wns, bns, out);
}

// Round 24
// 48.660 us; speedup vs baseline: 1.7464x; 1.1978x over previous
//
#include <hip/hip_runtime.h>
#include <hip/hip_bf16.h>

#define NROWS 16384   // B*S
#define KD    2048    // D
#define NE    16      // experts
#define ROWS_PER_BLK 64
#define KH    1024    // K-half resident in LDS
#define TPH   16      // tiles of 64 K-floats per half

// v21: barrier-free main loop. Diagnosis: v17/v18/v20 all ~57us with ~4.3k
// cy/tile vs ~1k pipe floor; the invariant is 1 barrier+vmcnt(0) drain per
// tile. Fix: W K-half (32 rows x 1024 = 128 KB) resident in LDS; stage once,
// then 16 tiles of pure XLOAD+ds_read+FMA with NO barriers; one re-stage for
// the second half (acc stays in regs). 3 barriers total (was 32).
//  - block = 512 thr / 8 waves / 64 rows; grid 256 = 1 block/CU
//  - wave w -> (expert-quartet eq=w&3, row-half rh=w>>2); x-dup 4x
//  - lane = (rgrp=lane>>3 -> 4 rows, seg=lane&7); acc = 32 floats (no-spill)
//  - FMA:ds_read = 16:1; LDS/tile/CU = 131 KB ~= FMA 1024 cy (balanced)
// Output FLOAT32: [262144 probs][32768 ids-as-floats].

__device__ __forceinline__ void gload_lds16(const float* g, float* l) {
    __builtin_amdgcn_global_load_lds(
        (const __attribute__((address_space(1))) void*)g,
        (__attribute__((address_space(3))) void*)l,
        16, 0, 0);
}

__global__ __launch_bounds__(512)
void noisy_router_kernel(const float* __restrict__ x,
                         const float* __restrict__ noise,
                         const float* __restrict__ Wfc,
                         const float* __restrict__ bfc,
                         const float* __restrict__ Wns,
                         const float* __restrict__ bns,
                         float* __restrict__ out)
{
    // [0, 32768): W-half [32 rows][1024];  [32768, 34880): epilogue slab [64][33]
    __shared__ float lds[32 * KH + ROWS_PER_BLK * 33];   // 139.5 KB

    const int tid  = threadIdx.x;
    const int lane = tid & 63;
    const int w    = tid >> 6;     // 0..7
    const int eq   = w & 3;        // expert quartet 0..3
    const int rh   = w >> 2;       // row half 0..1
    const int seg  = lane & 7;
    const int rgrp = lane >> 3;

    const int rowbase = blockIdx.x * ROWS_PER_BLK + rh * 32 + rgrp * 4;

    // staging map: instr i (0..15) writes W-stack rows {2i, 2i+1}:
    // thread tid -> row 2i + (tid>>8), col (tid&255)*4; dest = i*8KB + tid*16B
    // (uniform base + lane*16: legal form). Rows 0..15 = Wfc, 16..31 = Wns.
    const int wrb  = tid >> 8;             // 0 or 1
    const int scol = (tid & 255) * 4;

    const float* xb = x + (size_t)rowbase * KD + seg * 8;

    float accA[4][4], accB[4][4];          // 32 floats (proven no-spill size)
    #pragma unroll
    for (int j = 0; j < 4; ++j)
        #pragma unroll
        for (int e = 0; e < 4; ++e) { accA[j][e] = 0.f; accB[j][e] = 0.f; }

    #pragma unroll 1
    for (int h = 0; h < 2; ++h) {
        const int kbase = h * KH;
        __syncthreads();                       // phase boundary: all reads of prev half done
        {
            const float* srcF = Wfc + (size_t)wrb * KD + kbase + scol;   // i = 0..7
            const float* srcN = Wns + (size_t)wrb * KD + kbase + scol;   // i = 8..15
            #pragma unroll
            for (int i = 0; i < 8; ++i)
                gload_lds16(srcF + (size_t)(2 * i) * KD, lds + i * 2048 + tid * 4);
            #pragma unroll
            for (int i = 0; i < 8; ++i)
                gload_lds16(srcN + (size_t)(2 * i) * KD, lds + (8 + i) * 2048 + tid * 4);
        }
        __syncthreads();                       // W-half staged (vmcnt drained)

        const float* wp0 = lds + (eq * 4) * KH + seg * 8;        // Wfc rows
        const float* wp1 = lds + (16 + eq * 4) * KH + seg * 8;   // Wns rows
        const float* xh  = xb + kbase;

        // ---- 16 tiles, ZERO barriers: compiler free to pipeline loads ----
        #pragma unroll 2
        for (int t = 0; t < TPH; ++t) {
            float4 xv[4][2];
            #pragma unroll
            for (int j = 0; j < 4; ++j) {
                xv[j][0] = *(const float4*)(xh + (size_t)j * KD + t * 64);
                xv[j][1] = *(const float4*)(xh + (size_t)j * KD + t * 64 + 4);
            }
            #pragma unroll
            for (int e = 0; e < 4; ++e) {
                const float4 a0 = *(const float4*)(wp0 + e * KH + t * 64);
                const float4 a1 = *(const float4*)(wp0 + e * KH + t * 64 + 4);
                const float4 b0 = *(const float4*)(wp1 + e * KH + t * 64);
                const float4 b1 = *(const float4*)(wp1 + e * KH + t * 64 + 4);
                #pragma unroll
                for (int j = 0; j < 4; ++j) {
                    const float4 x0 = xv[j][0], x1 = xv[j][1];
                    float sA = accA[j][e], sB = accB[j][e];
                    sA = fmaf(x0.x, a0.x, sA); sA = fmaf(x0.y, a0.y, sA);
                    sA = fmaf(x0.z, a0.z, sA); sA = fmaf(x0.w, a0.w, sA);
                    sA = fmaf(x1.x, a1.x, sA); sA = fmaf(x1.y, a1.y, sA);
                    sA = fmaf(x1.z, a1.z, sA); sA = fmaf(x1.w, a1.w, sA);
                    sB = fmaf(x0.x, b0.x, sB); sB = fmaf(x0.y, b0.y, sB);
                    sB = fmaf(x0.z, b0.z, sB); sB = fmaf(x0.w, b0.w, sB);
                    sB = fmaf(x1.x, b1.x, sB); sB = fmaf(x1.y, b1.y, sB);
                    sB = fmaf(x1.z, b1.z, sB); sB = fmaf(x1.w, b1.w, sB);
                    accA[j][e] = sA; accB[j][e] = sB;
                }
            }
        }
    }

    // ---- butterfly over the 8 k-segs (masks 1,2,4 stay within seg-group) ----
    #pragma unroll
    for (int j = 0; j < 4; ++j)
        #pragma unroll
        for (int e = 0; e < 4; ++e) {
            float a = accA[j][e], b = accB[j][e];
            a += __shfl_xor(a, 1); a += __shfl_xor(a, 2); a += __shfl_xor(a, 4);
            b += __shfl_xor(b, 1); b += __shfl_xor(b, 2); b += __shfl_xor(b, 4);
            accA[j][e] = a; accB[j][e] = b;
        }

    __syncthreads();                  // all W reads done; slab region free anyway
    float* const slab = lds + 32 * KH;   // [64 rows][stride 33]

    if (seg == 0) {                   // each wave owns complete (row, e-quartet) outs
        #pragma unroll
        for (int j = 0; j < 4; ++j) {
            float* dst = slab + (rh * 32 + rgrp * 4 + j) * 33 + eq * 4;
            #pragma unroll
            for (int e = 0; e < 4; ++e) { dst[e] = accA[j][e]; dst[16 + e] = accB[j][e]; }
        }
    }
    __syncthreads();

    // ---- per-row epilogue: softplus noise, top-2, sparse softmax ----
    if (tid < ROWS_PER_BLK) {
        const int r = tid;
        const float* rowp = slab + r * 33;
        const size_t grow = (size_t)blockIdx.x * ROWS_PER_BLK + r;
        const float* nzp = noise + grow * NE;

        float m1 = -1e30f, m2 = -1e30f;
        int i1 = 0, i2 = 0;
        #pragma unroll
        for (int j = 0; j < NE; ++j) {
            const float z  = rowp[16 + j] + bns[j];
            const float sp = fmaxf(z, 0.f) + log1pf(expf(-fabsf(z)));  // jax softplus
            const float v  = fmaf(nzp[j], sp, rowp[j] + bfc[j]);
            if (v > m1)      { m2 = m1; i2 = i1; m1 = v; i1 = j; }     // ties -> lower idx
            else if (v > m2) { m2 = v;  i2 = j; }
        }
        const float e2  = expf(m2 - m1);
        const float inv = 1.f / (1.f + e2);

        float* po = out + grow * NE;
        #pragma unroll
        for (int j = 0; j < NE; ++j) {
            po[j] = (j == i1) ? inv : ((j == i2) ? e2 * inv : 0.f);
        }
        float* pi = out + (size_t)NROWS * NE + grow * 2;
        pi[0] = (float)i1;
        pi[1] = (float)i2;
    }
}

extern "C" void kernel_launch(void* const* d_in, const int* in_sizes, int n_in,
                              void* d_out, int out_size, void* d_ws, size_t ws_size,
                              hipStream_t stream)
{
    const float* x     = (const float*)d_in[0];
    const float* noise = (const float*)d_in[1];
    const float* Wfc   = (const float*)d_in[2];
    const float* bfc   = (const float*)d_in[3];
    const float* Wns   = (const float*)d_in[4];
    const float* bns   = (const float*)d_in[5];
    float* out = (float*)d_out;

    noisy_router_kernel<<<NROWS / ROWS_PER_BLK, 512, 0, stream>>>(
        x, noise, Wfc, bfc, Wns, bns, out);
}